// Round 2
// baseline (1725.733 us; speedup 1.0000x reference)
//
#include <hip/hip_runtime.h>
#include <math.h>

#define MD 1024
#define NWG_ADAM 32
#define BLK 512
#define TOTAL_BLOCKS 256
#define B_BLOCKS (TOTAL_BLOCKS - NWG_ADAM)      // 224
#define WAVES_PER_BLOCK (BLK / 64)              // 8
#define B_WAVES (B_BLOCKS * WAVES_PER_BLOCK)    // 1792
#define BS_ROWS 65536

// workspace float-index layout
//   [0,512)    : 32 flags, one per 16-float (64B) cacheline  (memset each launch)
//   [512,1536) : aa[1024]
//   [1536,1568): 32 inter1 partials
//   [1568,1792): 224 log-sigmoid partials
#define WS_AA_F 512
#define WS_I1_F 1536
#define WS_LS_F 1568
#define FLAG_STRIDE 16   // unsigneds per flag line (64 B)

__device__ __forceinline__ float aa_load(const float* p) {
  return __hip_atomic_load(p, __ATOMIC_RELAXED, __HIP_MEMORY_SCOPE_AGENT);
}
__device__ __forceinline__ void aa_store(float* p, float v) {
  __hip_atomic_store(p, v, __ATOMIC_RELAXED, __HIP_MEMORY_SCOPE_AGENT);
}

// Parallel-flag grid barrier across the NWG_ADAM blocks.
// Release: aa stores are sc1 (agent-coherent at completion); __syncthreads()
// drains vmcnt(0) per wave, so by the time wave 0 stores the flag, every
// wave's aa stores are globally visible. No L2 writeback flush needed.
// Acquire: aa reads are sc1 loads issued only after the poll succeeds.
__device__ __forceinline__ void grid_barrier(unsigned* flags, int b, unsigned gen) {
  __syncthreads();
  if (threadIdx.x < 64) {
    const int lane = (int)threadIdx.x;
    if (lane == 0)
      __hip_atomic_store(&flags[b * FLAG_STRIDE], gen,
                         __ATOMIC_RELAXED, __HIP_MEMORY_SCOPE_AGENT);
    unsigned v;
    do {
      v = (lane < NWG_ADAM)
            ? __hip_atomic_load(&flags[lane * FLAG_STRIDE],
                                __ATOMIC_RELAXED, __HIP_MEMORY_SCOPE_AGENT)
            : gen;
    } while (__any(v < gen));
    __builtin_amdgcn_fence(__ATOMIC_ACQUIRE, "agent");
  }
  __syncthreads();
}

__global__ __launch_bounds__(BLK, 2) void fused_kernel(
    const float* __restrict__ mean, const float* __restrict__ va,
    const float* __restrict__ xt, float* __restrict__ ws) {
  __shared__ float lds8[WAVES_PER_BLOCK];
  const int b = blockIdx.x;
  const int tid = (int)threadIdx.x;
  const int wv = tid >> 6;
  const int lane = tid & 63;
  unsigned* flags = (unsigned*)ws;
  float* aa = ws + WS_AA_F;

  if (b < NWG_ADAM) {
    // ---------------- Adam persistent blocks ----------------
    const int rbase = b * 32 + wv * 4;     // this wave owns rows rbase..rbase+3
    float q[4][16];                        // Qsym fragments: row r, cols lane*16..+15

    // row part (coalesced)
#pragma unroll
    for (int r = 0; r < 4; ++r) {
      const float4* rp = (const float4*)(va + (size_t)(rbase + r) * MD + lane * 16);
      float4 v0 = rp[0], v1 = rp[1], v2 = rp[2], v3 = rp[3];
      q[r][0] = v0.x; q[r][1] = v0.y; q[r][2]  = v0.z; q[r][3]  = v0.w;
      q[r][4] = v1.x; q[r][5] = v1.y; q[r][6]  = v1.z; q[r][7]  = v1.w;
      q[r][8] = v2.x; q[r][9] = v2.y; q[r][10] = v2.z; q[r][11] = v2.w;
      q[r][12] = v3.x; q[r][13] = v3.y; q[r][14] = v3.z; q[r][15] = v3.w;
    }
    // transpose part: va[col][rbase..rbase+3] is a contiguous float4
#pragma unroll
    for (int k = 0; k < 16; ++k) {
      float4 cv = *(const float4*)(va + (size_t)(lane * 16 + k) * MD + rbase);
      q[0][k] = 0.5f * (q[0][k] + cv.x);
      q[1][k] = 0.5f * (q[1][k] + cv.y);
      q[2][k] = 0.5f * (q[2][k] + cv.z);
      q[3][k] = 0.5f * (q[3][k] + cv.w);
    }

    const bool owner = (lane < 4);
    const int myrow = rbase + (lane & 3);
    const float mmy = owner ? mean[myrow] : 0.f;
    float wcur = 1.f, mo = 0.f, vo = 0.f;

    if (owner) aa_store(&aa[myrow], 1.f - mmy);   // aa_0 = w0 - mean
    unsigned gen = 1;
    grid_barrier(flags, b, gen); ++gen;

    float pb1 = 1.f, pb2 = 1.f;
    float p0, p1, p2, p3;

    for (int t = 1; t < 200; ++t) {
      float a[16];
#pragma unroll
      for (int k = 0; k < 16; ++k) a[k] = aa_load(aa + lane * 16 + k);
      p0 = 0.f; p1 = 0.f; p2 = 0.f; p3 = 0.f;
#pragma unroll
      for (int k = 0; k < 16; ++k) {
        p0 = fmaf(q[0][k], a[k], p0);
        p1 = fmaf(q[1][k], a[k], p1);
        p2 = fmaf(q[2][k], a[k], p2);
        p3 = fmaf(q[3][k], a[k], p3);
      }
#pragma unroll
      for (int m = 1; m < 64; m <<= 1) {
        p0 += __shfl_xor(p0, m);
        p1 += __shfl_xor(p1, m);
        p2 += __shfl_xor(p2, m);
        p3 += __shfl_xor(p3, m);
      }
      pb1 *= 0.9f; pb2 *= 0.999f;
      if (owner) {
        float g = (lane == 0) ? p0 : (lane == 1) ? p1 : (lane == 2) ? p2 : p3;
        mo = 0.9f * mo + 0.1f * g;
        vo = 0.999f * vo + 0.001f * (g * g);
        float mhat = mo / (1.f - pb1);
        float vhat = vo / (1.f - pb2);
        wcur -= 0.1f * mhat / (sqrtf(vhat) + 1e-8f);
        aa_store(&aa[myrow], wcur - mmy);
      }
      grid_barrier(flags, b, gen); ++gen;
    }

    // final inter1 partial: aa^T Qsym aa over owned rows
    {
      float a[16];
#pragma unroll
      for (int k = 0; k < 16; ++k) a[k] = aa_load(aa + lane * 16 + k);
      p0 = 0.f; p1 = 0.f; p2 = 0.f; p3 = 0.f;
#pragma unroll
      for (int k = 0; k < 16; ++k) {
        p0 = fmaf(q[0][k], a[k], p0);
        p1 = fmaf(q[1][k], a[k], p1);
        p2 = fmaf(q[2][k], a[k], p2);
        p3 = fmaf(q[3][k], a[k], p3);
      }
#pragma unroll
      for (int m = 1; m < 64; m <<= 1) {
        p0 += __shfl_xor(p0, m);
        p1 += __shfl_xor(p1, m);
        p2 += __shfl_xor(p2, m);
        p3 += __shfl_xor(p3, m);
      }
      float contrib = 0.f;
      if (owner) {
        float y = (lane == 0) ? p0 : (lane == 1) ? p1 : (lane == 2) ? p2 : p3;
        contrib = (wcur - mmy) * y;
      }
#pragma unroll
      for (int m = 1; m < 64; m <<= 1) contrib += __shfl_xor(contrib, m);
      if (lane == 0) lds8[wv] = contrib;
      __syncthreads();
      if (tid == 0) {
        float s = 0.f;
#pragma unroll
        for (int i = 0; i < WAVES_PER_BLOCK; ++i) s += lds8[i];
        ws[WS_I1_F + b] = s;
      }
    }
  } else {
    // ---------------- log-sigmoid streaming blocks ----------------
    const int gw = (b - NWG_ADAM) * WAVES_PER_BLOCK + wv;
    const float4* mp = (const float4*)mean;
    float4 m0 = mp[0 * 64 + lane];
    float4 m1 = mp[1 * 64 + lane];
    float4 m2 = mp[2 * 64 + lane];
    float4 m3 = mp[3 * 64 + lane];
    float lsum = 0.f;
    for (int row = gw; row < BS_ROWS; row += B_WAVES) {
      const float4* xr = (const float4*)(xt + (size_t)row * MD);
      float4 x0 = xr[0 * 64 + lane];
      float4 x1 = xr[1 * 64 + lane];
      float4 x2 = xr[2 * 64 + lane];
      float4 x3 = xr[3 * 64 + lane];
      float acc = 0.f;
      acc = fmaf(x0.x, m0.x, acc); acc = fmaf(x0.y, m0.y, acc);
      acc = fmaf(x0.z, m0.z, acc); acc = fmaf(x0.w, m0.w, acc);
      acc = fmaf(x1.x, m1.x, acc); acc = fmaf(x1.y, m1.y, acc);
      acc = fmaf(x1.z, m1.z, acc); acc = fmaf(x1.w, m1.w, acc);
      acc = fmaf(x2.x, m2.x, acc); acc = fmaf(x2.y, m2.y, acc);
      acc = fmaf(x2.z, m2.z, acc); acc = fmaf(x2.w, m2.w, acc);
      acc = fmaf(x3.x, m3.x, acc); acc = fmaf(x3.y, m3.y, acc);
      acc = fmaf(x3.z, m3.z, acc); acc = fmaf(x3.w, m3.w, acc);
#pragma unroll
      for (int m = 1; m < 64; m <<= 1) acc += __shfl_xor(acc, m);
      if (lane == 0) {
        float z = fminf(acc, 0.f);
        lsum += z - log1pf(expf(-fabsf(acc)));
      }
    }
    if (lane == 0) lds8[wv] = lsum;
    __syncthreads();
    if (tid == 0) {
      float s = 0.f;
#pragma unroll
      for (int i = 0; i < WAVES_PER_BLOCK; ++i) s += lds8[i];
      ws[WS_LS_F + (b - NWG_ADAM)] = s;
    }
  }
}

__global__ void finalize_kernel(const float* __restrict__ ws, float* __restrict__ out) {
  const int lane = (int)threadIdx.x & 63;
  float qsum = (lane < NWG_ADAM) ? ws[WS_I1_F + lane] : 0.f;
  float lssum = 0.f;
  for (int i = lane; i < B_BLOCKS; i += 64) lssum += ws[WS_LS_F + i];
#pragma unroll
  for (int m = 1; m < 64; m <<= 1) {
    qsum += __shfl_xor(qsum, m);
    lssum += __shfl_xor(lssum, m);
  }
  if (lane == 0) out[0] = 0.5f * qsum - lssum;
}

extern "C" void kernel_launch(void* const* d_in, const int* in_sizes, int n_in,
                              void* d_out, int out_size, void* d_ws, size_t ws_size,
                              hipStream_t stream) {
  (void)in_sizes; (void)n_in; (void)out_size; (void)ws_size;
  const float* mean = (const float*)d_in[0];
  const float* va   = (const float*)d_in[1];
  const float* xt   = (const float*)d_in[2];
  float* out = (float*)d_out;
  float* ws  = (float*)d_ws;

  // reset the flag region only (bytes [0, 2048))
  hipMemsetAsync(d_ws, 0, 2048, stream);
  fused_kernel<<<TOTAL_BLOCKS, BLK, 0, stream>>>(mean, va, xt, ws);
  finalize_kernel<<<1, 64, 0, stream>>>(ws, out);
}

// Round 3
// 482.496 us; speedup vs baseline: 3.5767x; 3.5767x over previous
//
#include <hip/hip_runtime.h>
#include <math.h>

#define MD 1024
#define NWG_ADAM 16
#define RPB 64                                  // rows per Adam block
#define RPW 8                                   // rows per wave
#define BLK 512
#define TOTAL_BLOCKS 256
#define B_BLOCKS (TOTAL_BLOCKS - NWG_ADAM)      // 240 streaming blocks
#define WAVES_PER_BLOCK (BLK / 64)              // 8
#define B_WAVES (B_BLOCKS * WAVES_PER_BLOCK)    // 1920
#define BS_ROWS 65536

// workspace layout:
//   bytes  [0, 16384): u64 tagbuf[2][1024]  (gen<<32 | float bits) - memset/launch
//   floats [4096, 4112): 16 inter1 partials
//   floats [4112, 4352): 240 log-sigmoid partials
#define WS_I1_F 4096
#define WS_LS_F 4112

typedef unsigned long long u64t;

__device__ __forceinline__ void tag_store(u64t* p, unsigned gen, float v) {
  u64t x = ((u64t)gen << 32) | (u64t)__float_as_uint(v);
  __hip_atomic_store(p, x, __ATOMIC_RELAXED, __HIP_MEMORY_SCOPE_AGENT);
}

// select-combine: lane keeps `a` or `b` per sel, sums partner's other half.
__device__ __forceinline__ float comb2(float a, float b, int sel, int m) {
  float keep = sel ? b : a;
  float send = sel ? a : b;
  return keep + __shfl_xor(send, m);
}

// p[0..7] per-lane partials -> lane l holds full 64-lane sum of row (l&7).
__device__ __forceinline__ float reduce8(const float p[8], int lane) {
  float c01 = comb2(p[0], p[1], lane & 1, 1);
  float c23 = comb2(p[2], p[3], lane & 1, 1);
  float c45 = comb2(p[4], p[5], lane & 1, 1);
  float c67 = comb2(p[6], p[7], lane & 1, 1);
  float d03 = comb2(c01, c23, lane & 2, 2);
  float d47 = comb2(c45, c67, lane & 2, 2);
  float e   = comb2(d03, d47, lane & 4, 4);
  e += __shfl_xor(e, 8);
  e += __shfl_xor(e, 16);
  e += __shfl_xor(e, 32);
  return e;
}

__global__ __launch_bounds__(BLK, 2) void fused_kernel(
    const float* __restrict__ mean, const float* __restrict__ va,
    const float* __restrict__ xt, float* __restrict__ ws) {
  __shared__ float aas[MD];
  __shared__ float lds8[WAVES_PER_BLOCK];
  const int b = blockIdx.x;
  const int tid = (int)threadIdx.x;
  const int wv = tid >> 6;
  const int lane = tid & 63;

  if (b < NWG_ADAM) {
    // ---------------- Adam persistent blocks ----------------
    u64t* tb = (u64t*)ws;                  // tagbuf[2][1024]
    const int rbase = b * RPB + wv * RPW;  // wave owns rows rbase..rbase+7
    // lane l holds Qsym[rbase+r][l + 64*j], r<8, j<16  (128 VGPRs)
    float q[8][16];
#pragma unroll
    for (int r = 0; r < 8; ++r)
#pragma unroll
      for (int j = 0; j < 16; ++j)
        q[r][j] = va[(size_t)(rbase + r) * MD + lane + 64 * j];
#pragma unroll
    for (int j = 0; j < 16; ++j) {
      const float* cp = va + (size_t)(lane + 64 * j) * MD + rbase;
      float4 c0 = *(const float4*)cp;
      float4 c1 = *(const float4*)(cp + 4);
      q[0][j] = 0.5f * (q[0][j] + c0.x);
      q[1][j] = 0.5f * (q[1][j] + c0.y);
      q[2][j] = 0.5f * (q[2][j] + c0.z);
      q[3][j] = 0.5f * (q[3][j] + c0.w);
      q[4][j] = 0.5f * (q[4][j] + c1.x);
      q[5][j] = 0.5f * (q[5][j] + c1.y);
      q[6][j] = 0.5f * (q[6][j] + c1.z);
      q[7][j] = 0.5f * (q[7][j] + c1.w);
    }

    const bool owner = (lane < RPW);
    const int myrow = rbase + lane;                 // valid when owner
    const float mmy = owner ? mean[myrow] : 0.f;
    float wcur = 1.f, mo = 0.f, vo = 0.f;

    if (owner) tag_store(tb + MD + myrow, 1u, 1.f - mmy);   // gen 1 -> buffer[1]

    float pb1 = 1.f, pb2 = 1.f;
    float a[16], p[8];

    for (unsigned t = 1; t <= 200; ++t) {
      // wave 0: poll parity buffer for gen==t, stage floats to LDS
      if (wv == 0) {
        const u64t* src = tb + (size_t)(t & 1u) * MD;
        u64t v[16];
        bool ok;
        do {
          ok = true;
#pragma unroll
          for (int j = 0; j < 16; ++j)
            v[j] = __hip_atomic_load(src + lane + 64 * j,
                                     __ATOMIC_RELAXED, __HIP_MEMORY_SCOPE_AGENT);
#pragma unroll
          for (int j = 0; j < 16; ++j) ok &= ((unsigned)(v[j] >> 32) == t);
        } while (__any(!ok));
#pragma unroll
        for (int j = 0; j < 16; ++j)
          aas[lane + 64 * j] = __uint_as_float((unsigned)v[j]);
      }
      __syncthreads();
#pragma unroll
      for (int j = 0; j < 16; ++j) a[j] = aas[lane + 64 * j];
#pragma unroll
      for (int r = 0; r < 8; ++r) {
        float s = 0.f;
#pragma unroll
        for (int j = 0; j < 16; ++j) s = fmaf(q[r][j], a[j], s);
        p[r] = s;
      }
      float e = reduce8(p, lane);   // lane l: g for row rbase+(l&7)

      if (t == 200) {
        // final: e = (Qsym aa)_row ; inter1 partial = sum aa_row * e
        float contrib = owner ? (wcur - mmy) * e : 0.f;
#pragma unroll
        for (int m = 1; m < 64; m <<= 1) contrib += __shfl_xor(contrib, m);
        if (lane == 0) lds8[wv] = contrib;
        __syncthreads();
        if (tid == 0) {
          float s = 0.f;
#pragma unroll
          for (int i = 0; i < WAVES_PER_BLOCK; ++i) s += lds8[i];
          ws[WS_I1_F + b] = s;
        }
        break;
      }

      pb1 *= 0.9f; pb2 *= 0.999f;
      if (owner) {
        mo = 0.9f * mo + 0.1f * e;
        vo = 0.999f * vo + 0.001f * (e * e);
        float mhat = mo / (1.f - pb1);
        float vhat = vo / (1.f - pb2);
        wcur -= 0.1f * mhat / (sqrtf(vhat) + 1e-8f);
        tag_store(tb + (size_t)((t + 1) & 1u) * MD + myrow, t + 1, wcur - mmy);
      }
    }
  } else {
    // ---------------- log-sigmoid streaming blocks ----------------
    const int gw = (b - NWG_ADAM) * WAVES_PER_BLOCK + wv;
    const float4* mp = (const float4*)mean;
    float4 m0 = mp[0 * 64 + lane];
    float4 m1 = mp[1 * 64 + lane];
    float4 m2 = mp[2 * 64 + lane];
    float4 m3 = mp[3 * 64 + lane];
    float lsum = 0.f;
    for (int row = gw; row < BS_ROWS; row += B_WAVES) {
      const float4* xr = (const float4*)(xt + (size_t)row * MD);
      float4 x0 = xr[0 * 64 + lane];
      float4 x1 = xr[1 * 64 + lane];
      float4 x2 = xr[2 * 64 + lane];
      float4 x3 = xr[3 * 64 + lane];
      float acc = 0.f;
      acc = fmaf(x0.x, m0.x, acc); acc = fmaf(x0.y, m0.y, acc);
      acc = fmaf(x0.z, m0.z, acc); acc = fmaf(x0.w, m0.w, acc);
      acc = fmaf(x1.x, m1.x, acc); acc = fmaf(x1.y, m1.y, acc);
      acc = fmaf(x1.z, m1.z, acc); acc = fmaf(x1.w, m1.w, acc);
      acc = fmaf(x2.x, m2.x, acc); acc = fmaf(x2.y, m2.y, acc);
      acc = fmaf(x2.z, m2.z, acc); acc = fmaf(x2.w, m2.w, acc);
      acc = fmaf(x3.x, m3.x, acc); acc = fmaf(x3.y, m3.y, acc);
      acc = fmaf(x3.z, m3.z, acc); acc = fmaf(x3.w, m3.w, acc);
#pragma unroll
      for (int m = 1; m < 64; m <<= 1) acc += __shfl_xor(acc, m);
      if (lane == 0) {
        float z = fminf(acc, 0.f);
        lsum += z - log1pf(expf(-fabsf(acc)));
      }
    }
    if (lane == 0) lds8[wv] = lsum;
    __syncthreads();
    if (tid == 0) {
      float s = 0.f;
#pragma unroll
      for (int i = 0; i < WAVES_PER_BLOCK; ++i) s += lds8[i];
      ws[WS_LS_F + (b - NWG_ADAM)] = s;
    }
  }
}

__global__ void finalize_kernel(const float* __restrict__ ws, float* __restrict__ out) {
  const int lane = (int)threadIdx.x & 63;
  float qsum = (lane < NWG_ADAM) ? ws[WS_I1_F + lane] : 0.f;
  float lssum = 0.f;
  for (int i = lane; i < B_BLOCKS; i += 64) lssum += ws[WS_LS_F + i];
#pragma unroll
  for (int m = 1; m < 64; m <<= 1) {
    qsum += __shfl_xor(qsum, m);
    lssum += __shfl_xor(lssum, m);
  }
  if (lane == 0) out[0] = 0.5f * qsum - lssum;
}

extern "C" void kernel_launch(void* const* d_in, const int* in_sizes, int n_in,
                              void* d_out, int out_size, void* d_ws, size_t ws_size,
                              hipStream_t stream) {
  (void)in_sizes; (void)n_in; (void)out_size; (void)ws_size;
  const float* mean = (const float*)d_in[0];
  const float* va   = (const float*)d_in[1];
  const float* xt   = (const float*)d_in[2];
  float* out = (float*)d_out;
  float* ws  = (float*)d_ws;

  // reset the tagged-aa double buffer (gens must start at 0 every launch)
  hipMemsetAsync(d_ws, 0, 2 * MD * sizeof(u64t), stream);
  fused_kernel<<<TOTAL_BLOCKS, BLK, 0, stream>>>(mean, va, xt, ws);
  finalize_kernel<<<1, 64, 0, stream>>>(ws, out);
}